// Round 11
// baseline (158.309 us; speedup 1.0000x reference)
//
#include <hip/hip_runtime.h>
#include <hip/hip_bf16.h>

// Problem constants
#define NB    8      // batch
#define CIN   128    // input channels = EMBED
#define SLEN  1600   // H*W
#define HEADS 8
#define HD    16     // head dim
#define NH    64     // NB*HEADS
#define VCH   17     // V channels incl. all-ones row (rowsum via MFMA col 16)

// ws element counts (all bf16)
#define XT_SUB   (NB * SLEN * CIN)      // 1,638,400  x^T  [n][s][c]
#define WQ_SUB   (3 * CIN * CIN)        // 49,152     w_qkv bf16 [m][k]
#define WO_SUB   (CIN * CIN)            // 16,384     w_o  bf16 [m][k]
#define QKV_SUB  (NH * HD * SLEN)       // 1,638,400  qT/kT [nh][s][c]
#define VB_SUB   (NH * VCH * SLEN)      // 1,740,800  V    [nh][17][s]
// abT [n][s][128] = XT_SUB.  Total ws = 16.7 MB (< 26.2 MB proven in R2).

// scale folded into Q at projection time: (1/sqrt(16)) * log2(e)
#define SCALE_Q 0.36067376022224085f

typedef __attribute__((ext_vector_type(8)))  short  short8;   // 8 bf16 = 4 VGPR
typedef __attribute__((ext_vector_type(16))) float  f32x16;
typedef __attribute__((ext_vector_type(2)))  unsigned uint2v;

__device__ inline unsigned short f2bf(float f) {
    union { float f; unsigned u; } x; x.f = f;
    unsigned r = x.u + 0x7FFFu + ((x.u >> 16) & 1u);   // RNE
    return (unsigned short)(r >> 16);
}

__device__ inline unsigned pkbf(float a, float b) {   // {bf16(a) lo, bf16(b) hi}
    __hip_bfloat162 h = __float22bfloat162_rn(make_float2(a, b));
    union { __hip_bfloat162 h; unsigned u; } c; c.h = h; return c.u;
}

__device__ inline short8 mk8(unsigned w0, unsigned w1, unsigned w2, unsigned w3) {
    union { unsigned u[4]; short8 s; } t;
    t.u[0] = w0; t.u[1] = w1; t.u[2] = w2; t.u[3] = w3; return t.s;
}

// ---------------------------------------------------------------------------
// Cast/transpose: x [n][c][s] fp32 -> xT [n][s][c] bf16 (blocks bx<25);
// bx==25: n==0 casts w_qkv, n==1 casts w_o (native [m][k] layout).
// Reads coalesced (wave spans 64 consecutive s per channel); writes 16B/lane.
// ---------------------------------------------------------------------------
__global__ __launch_bounds__(64) void cast_kernel(const float* __restrict__ x,
                                                  const float* __restrict__ w_qkv,
                                                  const float* __restrict__ w_o,
                                                  unsigned short* __restrict__ xT,
                                                  unsigned short* __restrict__ wq,
                                                  unsigned short* __restrict__ wo) {
    const int lane = threadIdx.x;
    const int bx = blockIdx.x;
    const int n = blockIdx.y;
    if (bx < 25) {
        const int s = bx * 64 + lane;
        const float* xp = x + n * (CIN * SLEN) + s;
        unsigned short* op = xT + (n * SLEN + s) * CIN;
#pragma unroll 4
        for (int c0 = 0; c0 < CIN; c0 += 8) {
            float v[8];
#pragma unroll
            for (int u = 0; u < 8; ++u) v[u] = xp[(c0 + u) * SLEN];
            union { unsigned short us[8]; uint4 u4; } t;
#pragma unroll
            for (int u = 0; u < 8; ++u) t.us[u] = f2bf(v[u]);
            *(uint4*)(op + c0) = t.u4;   // 16B store
        }
    } else if (n < 2) {
        const float* src = (n == 0) ? w_qkv : w_o;
        unsigned short* dst = (n == 0) ? wq : wo;
        const int cnt = (n == 0) ? WQ_SUB : WO_SUB;
        for (int i = lane * 4; i < cnt; i += 64 * 4) {
            float4 v = *(const float4*)(src + i);
            ushort4 w;
            w.x = f2bf(v.x); w.y = f2bf(v.y); w.z = f2bf(v.z); w.w = f2bf(v.w);
            *(ushort4*)(dst + i) = w;
        }
    }
}

// ---------------------------------------------------------------------------
// QKV GEMM, bf16 MFMA, no LDS (operands L1/L2-hot). Block = 6 waves, wave w
// owns m-rows [64w, 64w+64) x s-cols [s0, s0+64): 2x2 tiles of 32x32x16,
// K=128 = 8 chained steps. A = W[m][k] (16B frag/lane), B = xT[s][k] (16B).
// D[m][s]: col s = lane&31, row m = (e&3)+8*(e>>2)+4*(lane>>5). Epilogue
// scatters 4-row quads: q/k -> [nh][s][16] ushort4 (Q scaled), v -> [nh][17][s]
// scalars; wave 0 writes V ones-channel for its s-range.
// ---------------------------------------------------------------------------
__global__ __launch_bounds__(384) void qkv_gemm(const unsigned short* __restrict__ xT,
                                                const unsigned short* __restrict__ wq,
                                                unsigned short* __restrict__ qT,
                                                unsigned short* __restrict__ kT,
                                                unsigned short* __restrict__ vB) {
    const int tid = threadIdx.x;
    const int wave = tid >> 6;
    const int lane = tid & 63;
    const int l31 = lane & 31, g = lane >> 5;
    const int n = blockIdx.y;
    const int s0 = blockIdx.x * 64;
    const int m0 = wave * 64;

    const unsigned short* Ab = wq + (m0 + l31) * CIN + g * 8;
    const unsigned short* Bb = xT + (n * SLEN + s0 + l31) * CIN + g * 8;

    f32x16 acc00, acc01, acc10, acc11;
#pragma unroll
    for (int e = 0; e < 16; ++e) { acc00[e] = 0.f; acc01[e] = 0.f; acc10[e] = 0.f; acc11[e] = 0.f; }

#pragma unroll
    for (int ks = 0; ks < 8; ++ks) {
        short8 A0 = *(const short8*)(Ab + ks * 16);
        short8 A1 = *(const short8*)(Ab + 32 * CIN + ks * 16);
        short8 B0 = *(const short8*)(Bb + ks * 16);
        short8 B1 = *(const short8*)(Bb + 32 * CIN + ks * 16);
        acc00 = __builtin_amdgcn_mfma_f32_32x32x16_bf16(A0, B0, acc00, 0, 0, 0);
        acc01 = __builtin_amdgcn_mfma_f32_32x32x16_bf16(A0, B1, acc01, 0, 0, 0);
        acc10 = __builtin_amdgcn_mfma_f32_32x32x16_bf16(A1, B0, acc10, 0, 0, 0);
        acc11 = __builtin_amdgcn_mfma_f32_32x32x16_bf16(A1, B1, acc11, 0, 0, 0);
    }

#pragma unroll
    for (int mt = 0; mt < 2; ++mt)
#pragma unroll
        for (int st = 0; st < 2; ++st) {
            f32x16 a = mt ? (st ? acc11 : acc10) : (st ? acc01 : acc00);
            const int s = s0 + st * 32 + l31;
#pragma unroll
            for (int q = 0; q < 4; ++q) {
                int mb = m0 + mt * 32 + 8 * q + 4 * g;   // quad base (4-aligned)
                int h = mb / 48;
                int r48 = mb - h * 48;
                int which = r48 >> 4;
                int c0 = r48 & 15;
                int nh = n * HEADS + h;
                if (which == 2) {
#pragma unroll
                    for (int e = 0; e < 4; ++e)
                        vB[(nh * VCH + c0 + e) * SLEN + s] = f2bf(a[4 * q + e]);
                } else {
                    const float sc = (which == 0) ? SCALE_Q : 1.0f;
                    unsigned short* dst = ((which == 0) ? qT : kT) + nh * (SLEN * HD) + s * HD + c0;
                    ushort4 w;
                    w.x = f2bf(a[4 * q + 0] * sc); w.y = f2bf(a[4 * q + 1] * sc);
                    w.z = f2bf(a[4 * q + 2] * sc); w.w = f2bf(a[4 * q + 3] * sc);
                    *(ushort4*)dst = w;   // 8B store, 8B-aligned (c0 in {0,4,8,12})
                }
            }
        }

    // V ones-channel for this block's s-range
    if (wave == 0) {
        int s = s0 + lane;
#pragma unroll
        for (int h = 0; h < HEADS; ++h)
            vB[((n * HEADS + h) * VCH + 16) * SLEN + s] = 0x3F80;
    }
}

// ---------------------------------------------------------------------------
// Output projection GEMM: same skeleton, M=128 (2 waves), In = abT [n][s][128]
// bf16, W = wo bf16, out = fp32 [n][128][s] + bias. Stores coalesced along s.
// ---------------------------------------------------------------------------
__global__ __launch_bounds__(128) void out_gemm(const unsigned short* __restrict__ abT,
                                                const unsigned short* __restrict__ wo,
                                                const float* __restrict__ bias,
                                                float* __restrict__ out) {
    const int tid = threadIdx.x;
    const int wave = tid >> 6;
    const int lane = tid & 63;
    const int l31 = lane & 31, g = lane >> 5;
    const int n = blockIdx.y;
    const int s0 = blockIdx.x * 64;
    const int m0 = wave * 64;

    const unsigned short* Ab = wo + (m0 + l31) * CIN + g * 8;
    const unsigned short* Bb = abT + (n * SLEN + s0 + l31) * CIN + g * 8;

    f32x16 acc00, acc01, acc10, acc11;
#pragma unroll
    for (int e = 0; e < 16; ++e) { acc00[e] = 0.f; acc01[e] = 0.f; acc10[e] = 0.f; acc11[e] = 0.f; }

#pragma unroll
    for (int ks = 0; ks < 8; ++ks) {
        short8 A0 = *(const short8*)(Ab + ks * 16);
        short8 A1 = *(const short8*)(Ab + 32 * CIN + ks * 16);
        short8 B0 = *(const short8*)(Bb + ks * 16);
        short8 B1 = *(const short8*)(Bb + 32 * CIN + ks * 16);
        acc00 = __builtin_amdgcn_mfma_f32_32x32x16_bf16(A0, B0, acc00, 0, 0, 0);
        acc01 = __builtin_amdgcn_mfma_f32_32x32x16_bf16(A0, B1, acc01, 0, 0, 0);
        acc10 = __builtin_amdgcn_mfma_f32_32x32x16_bf16(A1, B0, acc10, 0, 0, 0);
        acc11 = __builtin_amdgcn_mfma_f32_32x32x16_bf16(A1, B1, acc11, 0, 0, 0);
    }

#pragma unroll
    for (int mt = 0; mt < 2; ++mt)
#pragma unroll
        for (int st = 0; st < 2; ++st) {
            f32x16 a = mt ? (st ? acc11 : acc10) : (st ? acc01 : acc00);
            const int s = s0 + st * 32 + l31;
#pragma unroll
            for (int q = 0; q < 4; ++q) {
                int mb = m0 + mt * 32 + 8 * q + 4 * g;
                float4 b = *(const float4*)(bias + mb);
                out[(n * CIN + mb + 0) * SLEN + s] = a[4 * q + 0] + b.x;
                out[(n * CIN + mb + 1) * SLEN + s] = a[4 * q + 1] + b.y;
                out[(n * CIN + mb + 2) * SLEN + s] = a[4 * q + 2] + b.z;
                out[(n * CIN + mb + 3) * SLEN + s] = a[4 * q + 3] + b.w;
            }
        }
}

// ---------------------------------------------------------------------------
// MFMA attention, zero-LDS (unchanged R8 core -- proven). 1 wave/block; wave
// owns 32 query rows, walks 1600 keys in 32-j steps. Swapped QK^T
// (mfma_32x32x16, K=c=16): lane (i=l31,g) holds S^T for its query at 16 j's.
// p = exp2(sT) (log2e folded into Q; fixed offset 0 cancels in O/rs).
// cvt_pk + 4x permlane32_swap(Plo,Phi) -> lane-local A-fragments (T12).
// PV as 2x mfma_32x32x16; B = V||ones||junk (col 16 = rowsum free).
// QK^T pipelined one step ahead; loads two ahead (tail overruns stay in ws).
// Epilogue: divide, cast bf16, store abT [n][s][128] for out_gemm.
// ---------------------------------------------------------------------------
__global__ __launch_bounds__(64) void attn_mfma(const unsigned short* __restrict__ qT,
                                                const unsigned short* __restrict__ kT,
                                                const unsigned short* __restrict__ vB,
                                                unsigned short* __restrict__ abT) {
    const int lane = threadIdx.x;
    const int l31 = lane & 31, g = lane >> 5;
    const int nh = blockIdx.y;
    const int i0 = blockIdx.x * 32;

    const unsigned short* qbase = qT + nh * (SLEN * HD);
    const unsigned short* kptr = kT + nh * (SLEN * HD) + l31 * HD + g * 8;
    const unsigned short* vptr = vB + nh * (VCH * SLEN) + l31 * SLEN + g * 8;

    short8 qf = *(const short8*)(qbase + (i0 + l31) * HD + g * 8);

    f32x16 zz;
#pragma unroll
    for (int e = 0; e < 16; ++e) zz[e] = 0.f;
    f32x16 ov = zz;   // O cols 0..15 = V channels, col 16 = rowsum

    short8 k1 = *(const short8*)kptr;
    short8 vA0 = *(const short8*)vptr;
    short8 vB0 = *(const short8*)(vptr + 16);
    f32x16 sC = __builtin_amdgcn_mfma_f32_32x32x16_bf16(k1, qf, zz, 0, 0, 0);
    k1 = *(const short8*)(kptr + 32 * HD);
    short8 vA1 = *(const short8*)(vptr + 32);
    short8 vB1 = *(const short8*)(vptr + 48);
    const unsigned short* kp2 = kptr + 64 * HD;
    const unsigned short* vp2 = vptr + 64;

    for (int js = 0; js < 50; ++js) {
        short8 k2  = *(const short8*)kp2;
        short8 vA2 = *(const short8*)vp2;
        short8 vB2 = *(const short8*)(vp2 + 16);
        kp2 += 32 * HD; vp2 += 32;

        f32x16 sN = __builtin_amdgcn_mfma_f32_32x32x16_bf16(k1, qf, zz, 0, 0, 0);

        float p[16];
#pragma unroll
        for (int r = 0; r < 16; ++r) p[r] = __builtin_amdgcn_exp2f(sC[r]);

        unsigned P01 = pkbf(p[0], p[1]),   P23 = pkbf(p[2], p[3]);
        unsigned P45 = pkbf(p[4], p[5]),   P67 = pkbf(p[6], p[7]);
        unsigned P89 = pkbf(p[8], p[9]),   P1011 = pkbf(p[10], p[11]);
        unsigned P1213 = pkbf(p[12], p[13]), P1415 = pkbf(p[14], p[15]);

        uint2v s1 = __builtin_amdgcn_permlane32_swap(P01,   P45,   false, false);
        uint2v s2 = __builtin_amdgcn_permlane32_swap(P23,   P67,   false, false);
        uint2v s3 = __builtin_amdgcn_permlane32_swap(P89,   P1213, false, false);
        uint2v s4 = __builtin_amdgcn_permlane32_swap(P1011, P1415, false, false);
        short8 A1 = mk8(s1[0], s2[0], s1[1], s2[1]);
        short8 A2 = mk8(s3[0], s4[0], s3[1], s4[1]);

        ov = __builtin_amdgcn_mfma_f32_32x32x16_bf16(A1, vA0, ov, 0, 0, 0);
        ov = __builtin_amdgcn_mfma_f32_32x32x16_bf16(A2, vB0, ov, 0, 0, 0);

        sC = sN;
        k1 = k2; vA0 = vA1; vB0 = vB1; vA1 = vA2; vB1 = vB2;
    }

    // epilogue: lane (ch=l31, g) holds O[i][ch] for i=(e&3)+8*(e>>2)+4g;
    // rowsum = col 16 (lanes 16/48, same-g). Divide, cast, store abT[s][128].
    const int src = 16 + (lane & 32);
    const int nb = nh >> 3, h = nh & 7;
#pragma unroll
    for (int e = 0; e < 16; ++e) {
        float r = __shfl(ov[e], src);
        if (l31 < 16) {
            int i = (e & 3) + 8 * (e >> 2) + 4 * g;
            abT[(nb * SLEN + i0 + i) * CIN + h * HD + l31] = f2bf(ov[e] / r);
        }
    }
}

// ---------------------------------------------------------------------------
extern "C" void kernel_launch(void* const* d_in, const int* in_sizes, int n_in,
                              void* d_out, int out_size, void* d_ws, size_t ws_size,
                              hipStream_t stream) {
    const float* x     = (const float*)d_in[0];  // [8][128][1600]
    const float* w_qkv = (const float*)d_in[1];  // [384][128]
    const float* w_o   = (const float*)d_in[2];  // [128][128]
    const float* b_o   = (const float*)d_in[3];  // [128]
    float* out = (float*)d_out;                  // [8][128][1600]

    unsigned short* xT  = (unsigned short*)d_ws;
    unsigned short* wq  = xT + XT_SUB;
    unsigned short* wo  = wq + WQ_SUB;
    unsigned short* qT  = wo + WO_SUB;
    unsigned short* kT  = qT + QKV_SUB;
    unsigned short* vB  = kT + QKV_SUB;
    unsigned short* abT = vB + VB_SUB;
    // total 8,359,936 bf16 = 16.7 MB

    cast_kernel<<<dim3(26, NB), 64, 0, stream>>>(x, w_qkv, w_o, xT, wq, wo);
    qkv_gemm<<<dim3(25, NB), 384, 0, stream>>>(xT, wq, qT, kT, vB);
    attn_mfma<<<dim3(50, NH), 64, 0, stream>>>(qT, kT, vB, abT);
    out_gemm<<<dim3(25, NB), 128, 0, stream>>>(abT, wo, b_o, out);
}

// Round 12
// 141.331 us; speedup vs baseline: 1.1201x; 1.1201x over previous
//
#include <hip/hip_runtime.h>
#include <hip/hip_bf16.h>

// Problem constants
#define NB    8      // batch
#define CIN   128    // input channels = EMBED
#define SLEN  1600   // H*W
#define HEADS 8
#define HD    16     // head dim
#define NH    64     // NB*HEADS
#define VCH   17     // V channels incl. all-ones row (rowsum via MFMA col 16)

// ws element counts (all bf16)
#define XT_SUB   (NB * SLEN * CIN)      // 1,638,400  x^T  [n][s][c]
#define WQ_SUB   (3 * CIN * CIN)        // 49,152     w_qkv bf16 [m][k]
#define WO_SUB   (CIN * CIN)            // 16,384     w_o  bf16 [m][k]
#define QKV_SUB  (NH * HD * SLEN)       // 1,638,400  qT/kT [nh][s][c]
#define VB_SUB   (NH * VCH * SLEN)      // 1,740,800  V    [nh][17][s]
// abT [n][s][128] = XT_SUB.  Total ws = 16.7 MB (< 26.2 MB proven in R2).

// scale folded into Q at projection time: (1/sqrt(16)) * log2(e)
#define SCALE_Q 0.36067376022224085f

typedef __attribute__((ext_vector_type(8)))  short  short8;   // 8 bf16 = 4 VGPR
typedef __attribute__((ext_vector_type(16))) float  f32x16;
typedef __attribute__((ext_vector_type(2)))  unsigned uint2v;

__device__ inline unsigned short f2bf(float f) {
    union { float f; unsigned u; } x; x.f = f;
    unsigned r = x.u + 0x7FFFu + ((x.u >> 16) & 1u);   // RNE
    return (unsigned short)(r >> 16);
}

__device__ inline unsigned pkbf(float a, float b) {   // {bf16(a) lo, bf16(b) hi}
    __hip_bfloat162 h = __float22bfloat162_rn(make_float2(a, b));
    union { __hip_bfloat162 h; unsigned u; } c; c.h = h; return c.u;
}

__device__ inline short8 mk8(unsigned w0, unsigned w1, unsigned w2, unsigned w3) {
    union { unsigned u[4]; short8 s; } t;
    t.u[0] = w0; t.u[1] = w1; t.u[2] = w2; t.u[3] = w3; return t.s;
}

// ---------------------------------------------------------------------------
// Cast/transpose: x [n][c][s] fp32 -> xT [n][s][c] bf16. 256 threads: wave w
// handles c-range [32w, 32w+32) for 64 consecutive s (reads coalesced along
// s; writes 16B/lane). bx==25: n==0 casts w_qkv, n==1 casts w_o. 800 waves.
// ---------------------------------------------------------------------------
__global__ __launch_bounds__(256) void cast_kernel(const float* __restrict__ x,
                                                   const float* __restrict__ w_qkv,
                                                   const float* __restrict__ w_o,
                                                   unsigned short* __restrict__ xT,
                                                   unsigned short* __restrict__ wq,
                                                   unsigned short* __restrict__ wo) {
    const int tid = threadIdx.x;
    const int bx = blockIdx.x;
    const int n = blockIdx.y;
    if (bx < 25) {
        const int s = bx * 64 + (tid & 63);
        const int c_base = (tid >> 6) * 32;
        const float* xp = x + n * (CIN * SLEN) + s;
        unsigned short* op = xT + (n * SLEN + s) * CIN;
#pragma unroll
        for (int c0 = c_base; c0 < c_base + 32; c0 += 8) {
            float v[8];
#pragma unroll
            for (int u = 0; u < 8; ++u) v[u] = xp[(c0 + u) * SLEN];
            union { unsigned short us[8]; uint4 u4; } t;
#pragma unroll
            for (int u = 0; u < 8; ++u) t.us[u] = f2bf(v[u]);
            *(uint4*)(op + c0) = t.u4;   // 16B store
        }
    } else if (n < 2) {
        const float* src = (n == 0) ? w_qkv : w_o;
        unsigned short* dst = (n == 0) ? wq : wo;
        const int cnt = (n == 0) ? WQ_SUB : WO_SUB;
        for (int i = tid * 4; i < cnt; i += 256 * 4) {
            float4 v = *(const float4*)(src + i);
            ushort4 w;
            w.x = f2bf(v.x); w.y = f2bf(v.y); w.z = f2bf(v.z); w.w = f2bf(v.w);
            *(ushort4*)(dst + i) = w;
        }
    }
}

// ---------------------------------------------------------------------------
// QKV GEMM, bf16 MFMA, no LDS (operands L1/L2-hot). Grid (50, NB), 6 waves;
// wave w owns m-rows [64w, 64w+64) x s-cols [s0, s0+32): 2x1 tiles of
// 32x32x16, K=128 = 8 steps. 2400 waves (~2.3/SIMD). D[m][s]: col s=lane&31,
// row m=(e&3)+8*(e>>2)+4*(lane>>5). Epilogue scatters quads: q/k ->
// [nh][s][16] ushort4 (Q scaled), v -> [nh][17][s]; wave0 writes ones-ch.
// ---------------------------------------------------------------------------
__global__ __launch_bounds__(384) void qkv_gemm(const unsigned short* __restrict__ xT,
                                                const unsigned short* __restrict__ wq,
                                                unsigned short* __restrict__ qT,
                                                unsigned short* __restrict__ kT,
                                                unsigned short* __restrict__ vB) {
    const int tid = threadIdx.x;
    const int wave = tid >> 6;
    const int lane = tid & 63;
    const int l31 = lane & 31, g = lane >> 5;
    const int n = blockIdx.y;
    const int s0 = blockIdx.x * 32;
    const int m0 = wave * 64;

    const unsigned short* Ab = wq + (m0 + l31) * CIN + g * 8;
    const unsigned short* Bb = xT + (n * SLEN + s0 + l31) * CIN + g * 8;

    f32x16 acc0, acc1;
#pragma unroll
    for (int e = 0; e < 16; ++e) { acc0[e] = 0.f; acc1[e] = 0.f; }

#pragma unroll
    for (int ks = 0; ks < 8; ++ks) {
        short8 A0 = *(const short8*)(Ab + ks * 16);
        short8 A1 = *(const short8*)(Ab + 32 * CIN + ks * 16);
        short8 B0 = *(const short8*)(Bb + ks * 16);
        acc0 = __builtin_amdgcn_mfma_f32_32x32x16_bf16(A0, B0, acc0, 0, 0, 0);
        acc1 = __builtin_amdgcn_mfma_f32_32x32x16_bf16(A1, B0, acc1, 0, 0, 0);
    }

    const int s = s0 + l31;
#pragma unroll
    for (int mt = 0; mt < 2; ++mt) {
        f32x16 a = mt ? acc1 : acc0;
#pragma unroll
        for (int q = 0; q < 4; ++q) {
            int mb = m0 + mt * 32 + 8 * q + 4 * g;   // quad base (4-aligned)
            int h = mb / 48;
            int r48 = mb - h * 48;
            int which = r48 >> 4;
            int c0 = r48 & 15;
            int nh = n * HEADS + h;
            if (which == 2) {
#pragma unroll
                for (int e = 0; e < 4; ++e)
                    vB[(nh * VCH + c0 + e) * SLEN + s] = f2bf(a[4 * q + e]);
            } else {
                const float sc = (which == 0) ? SCALE_Q : 1.0f;
                unsigned short* dst = ((which == 0) ? qT : kT) + nh * (SLEN * HD) + s * HD + c0;
                ushort4 w;
                w.x = f2bf(a[4 * q + 0] * sc); w.y = f2bf(a[4 * q + 1] * sc);
                w.z = f2bf(a[4 * q + 2] * sc); w.w = f2bf(a[4 * q + 3] * sc);
                *(ushort4*)dst = w;   // 8B store, 8B-aligned (c0 in {0,4,8,12})
            }
        }
    }

    // V ones-channel for this block's 32-s range
    if (wave == 0 && lane < 32) {
        int ss = s0 + lane;
#pragma unroll
        for (int h = 0; h < HEADS; ++h)
            vB[((n * HEADS + h) * VCH + 16) * SLEN + ss] = 0x3F80;
    }
}

// ---------------------------------------------------------------------------
// Output projection GEMM: grid (50, NB), 4 waves; wave owns 32m x 32s (one
// 32x32x16 tile, 8 K-steps). 1600 waves. fp32 out + bias, coalesced along s.
// ---------------------------------------------------------------------------
__global__ __launch_bounds__(256) void out_gemm(const unsigned short* __restrict__ abT,
                                                const unsigned short* __restrict__ wo,
                                                const float* __restrict__ bias,
                                                float* __restrict__ out) {
    const int tid = threadIdx.x;
    const int wave = tid >> 6;
    const int lane = tid & 63;
    const int l31 = lane & 31, g = lane >> 5;
    const int n = blockIdx.y;
    const int s0 = blockIdx.x * 32;
    const int m0 = wave * 32;

    const unsigned short* Ab = wo + (m0 + l31) * CIN + g * 8;
    const unsigned short* Bb = abT + (n * SLEN + s0 + l31) * CIN + g * 8;

    f32x16 acc;
#pragma unroll
    for (int e = 0; e < 16; ++e) acc[e] = 0.f;

#pragma unroll
    for (int ks = 0; ks < 8; ++ks) {
        short8 A0 = *(const short8*)(Ab + ks * 16);
        short8 B0 = *(const short8*)(Bb + ks * 16);
        acc = __builtin_amdgcn_mfma_f32_32x32x16_bf16(A0, B0, acc, 0, 0, 0);
    }

    const int s = s0 + l31;
#pragma unroll
    for (int q = 0; q < 4; ++q) {
        int mb = m0 + 8 * q + 4 * g;
        float4 b = *(const float4*)(bias + mb);
        out[(n * CIN + mb + 0) * SLEN + s] = acc[4 * q + 0] + b.x;
        out[(n * CIN + mb + 1) * SLEN + s] = acc[4 * q + 1] + b.y;
        out[(n * CIN + mb + 2) * SLEN + s] = acc[4 * q + 2] + b.z;
        out[(n * CIN + mb + 3) * SLEN + s] = acc[4 * q + 3] + b.w;
    }
}

// ---------------------------------------------------------------------------
// MFMA attention, split-K 2-way (R8 inner loop preserved byte-for-byte; only
// loop count 50->25 + per-wave key-range offsets are new). Block = 2 waves,
// grid (50, 64) -> 6400 waves (~25/CU vs 10/CU before -- the measured
// bottleneck was occupancy: 31%, VALUBusy 45%). Wave w handles keys
// [800w, 800w+800). Fixed-offset softmax (offset 0) makes partial numerators
// AND the col-16 rowsum additive across waves: wave1 dumps its partial ov to
// LDS, barrier, wave0 adds and runs the epilogue. Tail prefetches overrun
// into adjacent allocated ws (values unused; junk cols 17-31 never stored).
// ---------------------------------------------------------------------------
__global__ __launch_bounds__(128) void attn_mfma(const unsigned short* __restrict__ qT,
                                                 const unsigned short* __restrict__ kT,
                                                 const unsigned short* __restrict__ vB,
                                                 unsigned short* __restrict__ abT) {
    __shared__ float plds[64 * 16];   // wave1's partial ov (4 KB)

    const int tid = threadIdx.x;
    const int wave = tid >> 6;
    const int lane = tid & 63;
    const int l31 = lane & 31, g = lane >> 5;
    const int nh = blockIdx.y;
    const int i0 = blockIdx.x * 32;
    const int j0 = wave * 800;        // this wave's key range base

    const unsigned short* qbase = qT + nh * (SLEN * HD);
    const unsigned short* kptr = kT + nh * (SLEN * HD) + (j0 + l31) * HD + g * 8;
    const unsigned short* vptr = vB + nh * (VCH * SLEN) + l31 * SLEN + j0 + g * 8;

    short8 qf = *(const short8*)(qbase + (i0 + l31) * HD + g * 8);

    f32x16 zz;
#pragma unroll
    for (int e = 0; e < 16; ++e) zz[e] = 0.f;
    f32x16 ov = zz;   // O cols 0..15 = V channels, col 16 = rowsum

    short8 k1 = *(const short8*)kptr;
    short8 vA0 = *(const short8*)vptr;
    short8 vB0 = *(const short8*)(vptr + 16);
    f32x16 sC = __builtin_amdgcn_mfma_f32_32x32x16_bf16(k1, qf, zz, 0, 0, 0);
    k1 = *(const short8*)(kptr + 32 * HD);
    short8 vA1 = *(const short8*)(vptr + 32);
    short8 vB1 = *(const short8*)(vptr + 48);
    const unsigned short* kp2 = kptr + 64 * HD;
    const unsigned short* vp2 = vptr + 64;

    for (int js = 0; js < 25; ++js) {
        short8 k2  = *(const short8*)kp2;
        short8 vA2 = *(const short8*)vp2;
        short8 vB2 = *(const short8*)(vp2 + 16);
        kp2 += 32 * HD; vp2 += 32;

        f32x16 sN = __builtin_amdgcn_mfma_f32_32x32x16_bf16(k1, qf, zz, 0, 0, 0);

        float p[16];
#pragma unroll
        for (int r = 0; r < 16; ++r) p[r] = __builtin_amdgcn_exp2f(sC[r]);

        unsigned P01 = pkbf(p[0], p[1]),   P23 = pkbf(p[2], p[3]);
        unsigned P45 = pkbf(p[4], p[5]),   P67 = pkbf(p[6], p[7]);
        unsigned P89 = pkbf(p[8], p[9]),   P1011 = pkbf(p[10], p[11]);
        unsigned P1213 = pkbf(p[12], p[13]), P1415 = pkbf(p[14], p[15]);

        uint2v s1 = __builtin_amdgcn_permlane32_swap(P01,   P45,   false, false);
        uint2v s2 = __builtin_amdgcn_permlane32_swap(P23,   P67,   false, false);
        uint2v s3 = __builtin_amdgcn_permlane32_swap(P89,   P1213, false, false);
        uint2v s4 = __builtin_amdgcn_permlane32_swap(P1011, P1415, false, false);
        short8 A1 = mk8(s1[0], s2[0], s1[1], s2[1]);
        short8 A2 = mk8(s3[0], s4[0], s3[1], s4[1]);

        ov = __builtin_amdgcn_mfma_f32_32x32x16_bf16(A1, vA0, ov, 0, 0, 0);
        ov = __builtin_amdgcn_mfma_f32_32x32x16_bf16(A2, vB0, ov, 0, 0, 0);

        sC = sN;
        k1 = k2; vA0 = vA1; vB0 = vB1; vA1 = vA2; vB1 = vB2;
    }

    // split-K combine: wave1 -> LDS, barrier, wave0 adds (all additive:
    // fixed-offset softmax has no per-wave max state)
    if (wave == 1) {
#pragma unroll
        for (int qq = 0; qq < 4; ++qq) {
            float4 t;
            t.x = ov[4 * qq + 0]; t.y = ov[4 * qq + 1];
            t.z = ov[4 * qq + 2]; t.w = ov[4 * qq + 3];
            *(float4*)&plds[lane * 16 + 4 * qq] = t;
        }
    }
    __syncthreads();
    if (wave == 0) {
#pragma unroll
        for (int qq = 0; qq < 4; ++qq) {
            float4 t = *(const float4*)&plds[lane * 16 + 4 * qq];
            ov[4 * qq + 0] += t.x; ov[4 * qq + 1] += t.y;
            ov[4 * qq + 2] += t.z; ov[4 * qq + 3] += t.w;
        }
        // epilogue: lane (ch=l31, g) holds O[i][ch] for i=(e&3)+8*(e>>2)+4g;
        // rowsum = col 16 (lanes 16/48). Divide, cast, store abT[s][128].
        const int src = 16 + (lane & 32);
        const int nb = nh >> 3, h = nh & 7;
#pragma unroll
        for (int e = 0; e < 16; ++e) {
            float r = __shfl(ov[e], src);
            if (l31 < 16) {
                int i = (e & 3) + 8 * (e >> 2) + 4 * g;
                abT[(nb * SLEN + i0 + i) * CIN + h * HD + l31] = f2bf(ov[e] / r);
            }
        }
    }
}

// ---------------------------------------------------------------------------
extern "C" void kernel_launch(void* const* d_in, const int* in_sizes, int n_in,
                              void* d_out, int out_size, void* d_ws, size_t ws_size,
                              hipStream_t stream) {
    const float* x     = (const float*)d_in[0];  // [8][128][1600]
    const float* w_qkv = (const float*)d_in[1];  // [384][128]
    const float* w_o   = (const float*)d_in[2];  // [128][128]
    const float* b_o   = (const float*)d_in[3];  // [128]
    float* out = (float*)d_out;                  // [8][128][1600]

    unsigned short* xT  = (unsigned short*)d_ws;
    unsigned short* wq  = xT + XT_SUB;
    unsigned short* wo  = wq + WQ_SUB;
    unsigned short* qT  = wo + WO_SUB;
    unsigned short* kT  = qT + QKV_SUB;
    unsigned short* vB  = kT + QKV_SUB;
    unsigned short* abT = vB + VB_SUB;
    // total 8,359,936 bf16 = 16.7 MB

    cast_kernel<<<dim3(26, NB), 256, 0, stream>>>(x, w_qkv, w_o, xT, wq, wo);
    qkv_gemm<<<dim3(50, NB), 384, 0, stream>>>(xT, wq, qT, kT, vB);
    attn_mfma<<<dim3(50, NH), 128, 0, stream>>>(qT, kT, vB, abT);
    out_gemm<<<dim3(50, NB), 256, 0, stream>>>(abT, wo, b_o, out);
}

// Round 14
// 138.571 us; speedup vs baseline: 1.1424x; 1.0199x over previous
//
#include <hip/hip_runtime.h>
#include <hip/hip_bf16.h>

// Problem constants
#define NB    8      // batch
#define CIN   128    // input channels = EMBED
#define SLEN  1600   // H*W
#define HEADS 8
#define HD    16     // head dim
#define NH    64     // NB*HEADS
#define VCH   17     // V channels incl. all-ones row (rowsum via MFMA col 16)

// ws element counts (all bf16)
#define XT_SUB   (NB * SLEN * CIN)      // 1,638,400  x^T  [n][s][c]
#define WQ_SUB   (3 * CIN * CIN)        // 49,152     w_qkv bf16 [m][k]
#define WO_SUB   (CIN * CIN)            // 16,384     w_o  bf16 [m][k]
#define QKV_SUB  (NH * HD * SLEN)       // 1,638,400  qT/kT [nh][s][c]
#define VB_SUB   (NH * VCH * SLEN)      // 1,740,800  V    [nh][17][s]
// abT [n][s][128] = XT_SUB.  Total ws = 16.7 MB (< 26.2 MB proven in R2).

// scale folded into Q at projection time: (1/sqrt(16)) * log2(e)
#define SCALE_Q 0.36067376022224085f

typedef __attribute__((ext_vector_type(8)))  short  short8;   // 8 bf16 = 4 VGPR
typedef __attribute__((ext_vector_type(16))) float  f32x16;
typedef __attribute__((ext_vector_type(2)))  unsigned uint2v;

__device__ inline unsigned short f2bf(float f) {
    union { float f; unsigned u; } x; x.f = f;
    unsigned r = x.u + 0x7FFFu + ((x.u >> 16) & 1u);   // RNE
    return (unsigned short)(r >> 16);
}

__device__ inline unsigned pkbf(float a, float b) {   // {bf16(a) lo, bf16(b) hi}
    __hip_bfloat162 h = __float22bfloat162_rn(make_float2(a, b));
    union { __hip_bfloat162 h; unsigned u; } c; c.h = h; return c.u;
}

__device__ inline short8 mk8(unsigned w0, unsigned w1, unsigned w2, unsigned w3) {
    union { unsigned u[4]; short8 s; } t;
    t.u[0] = w0; t.u[1] = w1; t.u[2] = w2; t.u[3] = w3; return t.s;
}

// ---------------------------------------------------------------------------
// Cast/transpose: x [n][c][s] fp32 -> xT [n][s][c] bf16. 256 threads: wave w
// handles c-range [32w, 32w+32) for 64 consecutive s (reads coalesced along
// s; writes 16B/lane). bx==25: n==0 casts w_qkv, n==1 casts w_o. 800 waves.
// Stream-once, no inter-block reuse -> no XCD swizzle needed.
// ---------------------------------------------------------------------------
__global__ __launch_bounds__(256) void cast_kernel(const float* __restrict__ x,
                                                   const float* __restrict__ w_qkv,
                                                   const float* __restrict__ w_o,
                                                   unsigned short* __restrict__ xT,
                                                   unsigned short* __restrict__ wq,
                                                   unsigned short* __restrict__ wo) {
    const int tid = threadIdx.x;
    const int bx = blockIdx.x;
    const int n = blockIdx.y;
    if (bx < 25) {
        const int s = bx * 64 + (tid & 63);
        const int c_base = (tid >> 6) * 32;
        const float* xp = x + n * (CIN * SLEN) + s;
        unsigned short* op = xT + (n * SLEN + s) * CIN;
#pragma unroll
        for (int c0 = c_base; c0 < c_base + 32; c0 += 8) {
            float v[8];
#pragma unroll
            for (int u = 0; u < 8; ++u) v[u] = xp[(c0 + u) * SLEN];
            union { unsigned short us[8]; uint4 u4; } t;
#pragma unroll
            for (int u = 0; u < 8; ++u) t.us[u] = f2bf(v[u]);
            *(uint4*)(op + c0) = t.u4;   // 16B store
        }
    } else if (n < 2) {
        const float* src = (n == 0) ? w_qkv : w_o;
        unsigned short* dst = (n == 0) ? wq : wo;
        const int cnt = (n == 0) ? WQ_SUB : WO_SUB;
        for (int i = tid * 4; i < cnt; i += 256 * 4) {
            float4 v = *(const float4*)(src + i);
            ushort4 w;
            w.x = f2bf(v.x); w.y = f2bf(v.y); w.z = f2bf(v.z); w.w = f2bf(v.w);
            *(ushort4*)(dst + i) = w;
        }
    }
}

// ---------------------------------------------------------------------------
// QKV GEMM, bf16 MFMA, no LDS. Grid (NB, 50) -- XCD-swizzled: linear id =
// n + 8*stile, so xcd = n%8 and each XCD's blocks share ONE batch image's
// xT panel (400 KB << 4 MB L2). Wave w owns m-rows [64w,64w+64) x 32 s-cols.
// ---------------------------------------------------------------------------
__global__ __launch_bounds__(384) void qkv_gemm(const unsigned short* __restrict__ xT,
                                                const unsigned short* __restrict__ wq,
                                                unsigned short* __restrict__ qT,
                                                unsigned short* __restrict__ kT,
                                                unsigned short* __restrict__ vB) {
    const int tid = threadIdx.x;
    const int wave = tid >> 6;
    const int lane = tid & 63;
    const int l31 = lane & 31, g = lane >> 5;
    const int n = blockIdx.x;               // T1: batch on x -> xcd = n%8
    const int s0 = blockIdx.y * 32;
    const int m0 = wave * 64;

    const unsigned short* Ab = wq + (m0 + l31) * CIN + g * 8;
    const unsigned short* Bb = xT + (n * SLEN + s0 + l31) * CIN + g * 8;

    f32x16 acc0, acc1;
#pragma unroll
    for (int e = 0; e < 16; ++e) { acc0[e] = 0.f; acc1[e] = 0.f; }

#pragma unroll
    for (int ks = 0; ks < 8; ++ks) {
        short8 A0 = *(const short8*)(Ab + ks * 16);
        short8 A1 = *(const short8*)(Ab + 32 * CIN + ks * 16);
        short8 B0 = *(const short8*)(Bb + ks * 16);
        acc0 = __builtin_amdgcn_mfma_f32_32x32x16_bf16(A0, B0, acc0, 0, 0, 0);
        acc1 = __builtin_amdgcn_mfma_f32_32x32x16_bf16(A1, B0, acc1, 0, 0, 0);
    }

    const int s = s0 + l31;
#pragma unroll
    for (int mt = 0; mt < 2; ++mt) {
        f32x16 a = mt ? acc1 : acc0;
#pragma unroll
        for (int q = 0; q < 4; ++q) {
            int mb = m0 + mt * 32 + 8 * q + 4 * g;   // quad base (4-aligned)
            int h = mb / 48;
            int r48 = mb - h * 48;
            int which = r48 >> 4;
            int c0 = r48 & 15;
            int nh = n * HEADS + h;
            if (which == 2) {
#pragma unroll
                for (int e = 0; e < 4; ++e)
                    vB[(nh * VCH + c0 + e) * SLEN + s] = f2bf(a[4 * q + e]);
            } else {
                const float sc = (which == 0) ? SCALE_Q : 1.0f;
                unsigned short* dst = ((which == 0) ? qT : kT) + nh * (SLEN * HD) + s * HD + c0;
                ushort4 w;
                w.x = f2bf(a[4 * q + 0] * sc); w.y = f2bf(a[4 * q + 1] * sc);
                w.z = f2bf(a[4 * q + 2] * sc); w.w = f2bf(a[4 * q + 3] * sc);
                *(ushort4*)dst = w;   // 8B store, 8B-aligned (c0 in {0,4,8,12})
            }
        }
    }

    // V ones-channel for this block's 32-s range
    if (wave == 0 && lane < 32) {
        int ss = s0 + lane;
#pragma unroll
        for (int h = 0; h < HEADS; ++h)
            vB[((n * HEADS + h) * VCH + 16) * SLEN + ss] = 0x3F80;
    }
}

// ---------------------------------------------------------------------------
// Output projection GEMM: grid (NB, 50), XCD-swizzled like qkv_gemm (xcd =
// n%8; per-XCD abT panel 400 KB). 4 waves; wave owns 32m x 32s.
// ---------------------------------------------------------------------------
__global__ __launch_bounds__(256) void out_gemm(const unsigned short* __restrict__ abT,
                                                const unsigned short* __restrict__ wo,
                                                const float* __restrict__ bias,
                                                float* __restrict__ out) {
    const int tid = threadIdx.x;
    const int wave = tid >> 6;
    const int lane = tid & 63;
    const int l31 = lane & 31, g = lane >> 5;
    const int n = blockIdx.x;               // T1: batch on x -> xcd = n%8
    const int s0 = blockIdx.y * 32;
    const int m0 = wave * 32;

    const unsigned short* Ab = wo + (m0 + l31) * CIN + g * 8;
    const unsigned short* Bb = abT + (n * SLEN + s0 + l31) * CIN + g * 8;

    f32x16 acc;
#pragma unroll
    for (int e = 0; e < 16; ++e) acc[e] = 0.f;

#pragma unroll
    for (int ks = 0; ks < 8; ++ks) {
        short8 A0 = *(const short8*)(Ab + ks * 16);
        short8 B0 = *(const short8*)(Bb + ks * 16);
        acc = __builtin_amdgcn_mfma_f32_32x32x16_bf16(A0, B0, acc, 0, 0, 0);
    }

    const int s = s0 + l31;
#pragma unroll
    for (int q = 0; q < 4; ++q) {
        int mb = m0 + 8 * q + 4 * g;
        float4 b = *(const float4*)(bias + mb);
        out[(n * CIN + mb + 0) * SLEN + s] = acc[4 * q + 0] + b.x;
        out[(n * CIN + mb + 1) * SLEN + s] = acc[4 * q + 1] + b.y;
        out[(n * CIN + mb + 2) * SLEN + s] = acc[4 * q + 2] + b.z;
        out[(n * CIN + mb + 3) * SLEN + s] = acc[4 * q + 3] + b.w;
    }
}

// ---------------------------------------------------------------------------
// MFMA attention, split-K 2-way (R12 inner loop byte-identical). Grid is now
// (NH, 50) -- T1 XCD swizzle: linear id = nh + 64*i0tile, 64%8==0 so
// xcd = nh%8 and ALL 50 blocks sharing one head's K/V panel (105 KB,
// re-read 50x) land on the SAME XCD. Per-XCD working set = 8 heads ~1.25 MB
// << 4 MB L2 (R12 measured 3x HBM over-fetch = cross-XCD L2 thrash;
// FETCH_SIZE 29.3 MB vs ~10 MB inputs). Wave w handles keys [800w, 800w+800);
// fixed-offset softmax makes partials additive; wave1 -> LDS -> wave0 adds.
// ---------------------------------------------------------------------------
__global__ __launch_bounds__(128) void attn_mfma(const unsigned short* __restrict__ qT,
                                                 const unsigned short* __restrict__ kT,
                                                 const unsigned short* __restrict__ vB,
                                                 unsigned short* __restrict__ abT) {
    __shared__ float plds[64 * 16];   // wave1's partial ov (4 KB)

    const int tid = threadIdx.x;
    const int wave = tid >> 6;
    const int lane = tid & 63;
    const int l31 = lane & 31, g = lane >> 5;
    const int nh = blockIdx.x;        // T1: head on x -> xcd = nh%8
    const int i0 = blockIdx.y * 32;
    const int j0 = wave * 800;        // this wave's key range base

    const unsigned short* qbase = qT + nh * (SLEN * HD);
    const unsigned short* kptr = kT + nh * (SLEN * HD) + (j0 + l31) * HD + g * 8;
    const unsigned short* vptr = vB + nh * (VCH * SLEN) + l31 * SLEN + j0 + g * 8;

    short8 qf = *(const short8*)(qbase + (i0 + l31) * HD + g * 8);

    f32x16 zz;
#pragma unroll
    for (int e = 0; e < 16; ++e) zz[e] = 0.f;
    f32x16 ov = zz;   // O cols 0..15 = V channels, col 16 = rowsum

    short8 k1 = *(const short8*)kptr;
    short8 vA0 = *(const short8*)vptr;
    short8 vB0 = *(const short8*)(vptr + 16);
    f32x16 sC = __builtin_amdgcn_mfma_f32_32x32x16_bf16(k1, qf, zz, 0, 0, 0);
    k1 = *(const short8*)(kptr + 32 * HD);
    short8 vA1 = *(const short8*)(vptr + 32);
    short8 vB1 = *(const short8*)(vptr + 48);
    const unsigned short* kp2 = kptr + 64 * HD;
    const unsigned short* vp2 = vptr + 64;

    for (int js = 0; js < 25; ++js) {
        short8 k2  = *(const short8*)kp2;
        short8 vA2 = *(const short8*)vp2;
        short8 vB2 = *(const short8*)(vp2 + 16);
        kp2 += 32 * HD; vp2 += 32;

        f32x16 sN = __builtin_amdgcn_mfma_f32_32x32x16_bf16(k1, qf, zz, 0, 0, 0);

        float p[16];
#pragma unroll
        for (int r = 0; r < 16; ++r) p[r] = __builtin_amdgcn_exp2f(sC[r]);

        unsigned P01 = pkbf(p[0], p[1]),   P23 = pkbf(p[2], p[3]);
        unsigned P45 = pkbf(p[4], p[5]),   P67 = pkbf(p[6], p[7]);
        unsigned P89 = pkbf(p[8], p[9]),   P1011 = pkbf(p[10], p[11]);
        unsigned P1213 = pkbf(p[12], p[13]), P1415 = pkbf(p[14], p[15]);

        uint2v s1 = __builtin_amdgcn_permlane32_swap(P01,   P45,   false, false);
        uint2v s2 = __builtin_amdgcn_permlane32_swap(P23,   P67,   false, false);
        uint2v s3 = __builtin_amdgcn_permlane32_swap(P89,   P1213, false, false);
        uint2v s4 = __builtin_amdgcn_permlane32_swap(P1011, P1415, false, false);
        short8 A1 = mk8(s1[0], s2[0], s1[1], s2[1]);
        short8 A2 = mk8(s3[0], s4[0], s3[1], s4[1]);

        ov = __builtin_amdgcn_mfma_f32_32x32x16_bf16(A1, vA0, ov, 0, 0, 0);
        ov = __builtin_amdgcn_mfma_f32_32x32x16_bf16(A2, vB0, ov, 0, 0, 0);

        sC = sN;
        k1 = k2; vA0 = vA1; vB0 = vB1; vA1 = vA2; vB1 = vB2;
    }

    // split-K combine: wave1 -> LDS, barrier, wave0 adds (all additive:
    // fixed-offset softmax has no per-wave max state)
    if (wave == 1) {
#pragma unroll
        for (int qq = 0; qq < 4; ++qq) {
            float4 t;
            t.x = ov[4 * qq + 0]; t.y = ov[4 * qq + 1];
            t.z = ov[4 * qq + 2]; t.w = ov[4 * qq + 3];
            *(float4*)&plds[lane * 16 + 4 * qq] = t;
        }
    }
    __syncthreads();
    if (wave == 0) {
#pragma unroll
        for (int qq = 0; qq < 4; ++qq) {
            float4 t = *(const float4*)&plds[lane * 16 + 4 * qq];
            ov[4 * qq + 0] += t.x; ov[4 * qq + 1] += t.y;
            ov[4 * qq + 2] += t.z; ov[4 * qq + 3] += t.w;
        }
        // epilogue: lane (ch=l31, g) holds O[i][ch] for i=(e&3)+8*(e>>2)+4g;
        // rowsum = col 16 (lanes 16/48). Divide, cast, store abT[s][128].
        const int src = 16 + (lane & 32);
        const int nb = nh >> 3, h = nh & 7;
#pragma unroll
        for (int e = 0; e < 16; ++e) {
            float r = __shfl(ov[e], src);
            if (l31 < 16) {
                int i = (e & 3) + 8 * (e >> 2) + 4 * g;
                abT[(nb * SLEN + i0 + i) * CIN + h * HD + l31] = f2bf(ov[e] / r);
            }
        }
    }
}

// ---------------------------------------------------------------------------
extern "C" void kernel_launch(void* const* d_in, const int* in_sizes, int n_in,
                              void* d_out, int out_size, void* d_ws, size_t ws_size,
                              hipStream_t stream) {
    const float* x     = (const float*)d_in[0];  // [8][128][1600]
    const float* w_qkv = (const float*)d_in[1];  // [384][128]
    const float* w_o   = (const float*)d_in[2];  // [128][128]
    const float* b_o   = (const float*)d_in[3];  // [128]
    float* out = (float*)d_out;                  // [8][128][1600]

    unsigned short* xT  = (unsigned short*)d_ws;
    unsigned short* wq  = xT + XT_SUB;
    unsigned short* wo  = wq + WQ_SUB;
    unsigned short* qT  = wo + WO_SUB;
    unsigned short* kT  = qT + QKV_SUB;
    unsigned short* vB  = kT + QKV_SUB;
    unsigned short* abT = vB + VB_SUB;
    // total 8,359,936 bf16 = 16.7 MB

    cast_kernel<<<dim3(26, NB), 256, 0, stream>>>(x, w_qkv, w_o, xT, wq, wo);
    qkv_gemm<<<dim3(NB, 50), 384, 0, stream>>>(xT, wq, qT, kT, vB);     // T1 swizzle
    attn_mfma<<<dim3(NH, 50), 128, 0, stream>>>(qT, kT, vB, abT);       // T1 swizzle
    out_gemm<<<dim3(NB, 50), 256, 0, stream>>>(abT, wo, b_o, out);      // T1 swizzle
}